// Round 1
// baseline (6994.141 us; speedup 1.0000x reference)
//
#include <hip/hip_runtime.h>
#include <hip/hip_bf16.h>
#include <math.h>

// Problem constants (fixed by setup_inputs)
#define M_TOTAL 6272   // B*P
#define N_CS    16384  // coreset rows
#define D_DIM   384
#define BATCH   8
#define P_PATCH 784
#define KNN     9

// GEMM tiling
#define NC    32            // coreset chunks (grid.y)
#define CHUNK (N_CS / NC)   // 512
#define MT    128
#define NT    128
#define BK    32
#define LDSS  (MT + 4)      // 132 floats: keeps float4 alignment, modest conflicts

// ---------------------------------------------------------------- norms ----
// one wave per row (coalesced 64-lane reads), rows = coreset then patches
__global__ void norms_kernel(const float* __restrict__ emb,
                             const float* __restrict__ cs,
                             float* __restrict__ pnorm,
                             float* __restrict__ cnorm) {
    int gw   = (blockIdx.x * blockDim.x + threadIdx.x) >> 6;
    int lane = threadIdx.x & 63;
    if (gw >= M_TOTAL + N_CS) return;
    const float* row = (gw < N_CS) ? cs + (size_t)gw * D_DIM
                                   : emb + (size_t)(gw - N_CS) * D_DIM;
    float s = 0.f;
#pragma unroll
    for (int i = 0; i < D_DIM / 64; ++i) {
        float v = row[lane + i * 64];
        s += v * v;
    }
#pragma unroll
    for (int off = 32; off > 0; off >>= 1) s += __shfl_down(s, off, 64);
    if (lane == 0) {
        if (gw < N_CS) cnorm[gw] = s;
        else           pnorm[gw - N_CS] = s;
    }
}

// ------------------------------------------------- fused GEMM + min/argmin -
// block = 256 threads (16x16), 8x8 microtile -> 128x128 output tile.
// grid = (M/MT, NC). Each block scans its coreset chunk and writes one
// partial (minval, argmin) per patch row.
__global__ __launch_bounds__(256, 4) void mindist_kernel(
    const float* __restrict__ emb, const float* __restrict__ cs,
    const float* __restrict__ cnorm,
    float* __restrict__ pvals, int* __restrict__ pidx) {
    __shared__ float As[BK][LDSS];
    __shared__ float Bs[BK][LDSS];

    const int tid  = threadIdx.x;
    const int tx   = tid & 15;    // col group
    const int ty   = tid >> 4;    // row group
    const int row0 = blockIdx.x * MT;
    const int chunk = blockIdx.y;
    const int cbase0 = chunk * CHUNK;

    // loader mapping: 8 threads cover 32 consecutive k-floats of one row
    const int kg = tid & 7;
    const int m0 = tid >> 3;   // 0..31, rows m0 + 32*q

    float minv[8];
    int   mini[8];
#pragma unroll
    for (int i = 0; i < 8; ++i) { minv[i] = 3.4e38f; mini[i] = 0; }

    for (int it = 0; it < CHUNK / NT; ++it) {
        const int cbase = cbase0 + it * NT;

        float acc[8][8];
#pragma unroll
        for (int i = 0; i < 8; ++i)
#pragma unroll
            for (int j = 0; j < 8; ++j) acc[i][j] = 0.f;

        float cn[8];
#pragma unroll
        for (int j = 0; j < 8; ++j) cn[j] = cnorm[cbase + tx * 8 + j];

        for (int kk = 0; kk < D_DIM; kk += BK) {
            __syncthreads();
#pragma unroll
            for (int q = 0; q < 4; ++q) {
                int m = m0 + 32 * q;
                float4 av = *(const float4*)&emb[(size_t)(row0 + m) * D_DIM + kk + kg * 4];
                As[kg * 4 + 0][m] = av.x; As[kg * 4 + 1][m] = av.y;
                As[kg * 4 + 2][m] = av.z; As[kg * 4 + 3][m] = av.w;
                float4 bv = *(const float4*)&cs[(size_t)(cbase + m) * D_DIM + kk + kg * 4];
                Bs[kg * 4 + 0][m] = bv.x; Bs[kg * 4 + 1][m] = bv.y;
                Bs[kg * 4 + 2][m] = bv.z; Bs[kg * 4 + 3][m] = bv.w;
            }
            __syncthreads();
#pragma unroll
            for (int k = 0; k < BK; ++k) {
                float4 a0 = *(const float4*)&As[k][ty * 8];
                float4 a1 = *(const float4*)&As[k][ty * 8 + 4];
                float4 b0 = *(const float4*)&Bs[k][tx * 8];
                float4 b1 = *(const float4*)&Bs[k][tx * 8 + 4];
                float a[8] = {a0.x, a0.y, a0.z, a0.w, a1.x, a1.y, a1.z, a1.w};
                float b[8] = {b0.x, b0.y, b0.z, b0.w, b1.x, b1.y, b1.z, b1.w};
#pragma unroll
                for (int i = 0; i < 8; ++i)
#pragma unroll
                    for (int j = 0; j < 8; ++j) acc[i][j] += a[i] * b[j];
            }
        }
        // fold into running min (visit order = ascending col index per thread)
#pragma unroll
        for (int i = 0; i < 8; ++i) {
#pragma unroll
            for (int j = 0; j < 8; ++j) {
                float d = cn[j] - 2.f * acc[i][j];   // dist^2 - pnorm (monotone)
                int   c = cbase + tx * 8 + j;
                if (d < minv[i]) { minv[i] = d; mini[i] = c; }
            }
        }
    }

    // cross-tx reduction per row (reuse As/Bs as scratch)
    __syncthreads();
    float* redv = &As[0][0];
    int*   redi = (int*)&Bs[0][0];
#pragma unroll
    for (int i = 0; i < 8; ++i) {
        int r = ty * 8 + i;
        redv[r * 16 + tx] = minv[i];
        redi[r * 16 + tx] = mini[i];
    }
    __syncthreads();
    if (tid < 128) {
        int r = tid;
        float bv = redv[r * 16];
        int   bi = redi[r * 16];
        for (int x = 1; x < 16; ++x) {
            float v = redv[r * 16 + x];
            int  ii = redi[r * 16 + x];
            if (v < bv || (v == bv && ii < bi)) { bv = v; bi = ii; }
        }
        pvals[(size_t)(row0 + r) * NC + chunk] = bv;
        pidx[(row0 + r) * NC + chunk] = bi;
    }
}

// ------------------------------------------- partial-min reduce + score ----
__global__ void reduce_kernel(const float* __restrict__ pvals,
                              const int* __restrict__ pidx,
                              const float* __restrict__ pnorm,
                              float* __restrict__ scores, int* __restrict__ loc) {
    int m = blockIdx.x * blockDim.x + threadIdx.x;
    if (m >= M_TOTAL) return;
    float bv = pvals[(size_t)m * NC];
    int   bi = pidx[(size_t)m * NC];
    for (int c = 1; c < NC; ++c) {
        float v = pvals[(size_t)m * NC + c];
        int  ii = pidx[(size_t)m * NC + c];
        if (v < bv || (v == bv && ii < bi)) { bv = v; bi = ii; }
    }
    scores[m] = sqrtf(fmaxf(pnorm[m] + bv, 0.f));
    loc[m] = bi;
}

// ---------------------------------------------------- per-batch argmax ----
__global__ void argmax_kernel(const float* __restrict__ scores,
                              const int* __restrict__ loc,
                              float* __restrict__ bscore,
                              int* __restrict__ bnn, int* __restrict__ bpatch) {
    int b = blockIdx.x;
    int tid = threadIdx.x;
    float bv = -1.f;
    int bp = 0x7fffffff;
    for (int p = tid; p < P_PATCH; p += 256) {
        float v = scores[b * P_PATCH + p];
        if (v > bv || (v == bv && p < bp)) { bv = v; bp = p; }
    }
    __shared__ float sv[256];
    __shared__ int   sp[256];
    sv[tid] = bv; sp[tid] = bp;
    __syncthreads();
    for (int off = 128; off > 0; off >>= 1) {
        if (tid < off) {
            float v = sv[tid + off]; int p = sp[tid + off];
            if (v > sv[tid] || (v == sv[tid] && p < sp[tid])) { sv[tid] = v; sp[tid] = p; }
        }
        __syncthreads();
    }
    if (tid == 0) {
        bscore[b] = sv[0];
        bpatch[b] = sp[0];
        bnn[b]    = loc[b * P_PATCH + sp[0]];
    }
}

// --------------------------------- 9-NN in coreset + softmax weighting ----
__device__ inline void merge9(float* av, int* ai, const float* bv, const int* bi) {
    float mv[KNN]; int mi[KNN];
    int x = 0, y = 0;
#pragma unroll
    for (int k = 0; k < KNN; ++k) {
        bool ta = (av[x] < bv[y]) || (av[x] == bv[y] && ai[x] < bi[y]);
        if (ta) { mv[k] = av[x]; mi[k] = ai[x]; ++x; }
        else    { mv[k] = bv[y]; mi[k] = bi[y]; ++y; }
    }
#pragma unroll
    for (int k = 0; k < KNN; ++k) { av[k] = mv[k]; ai[k] = mi[k]; }
}

__global__ void knn_kernel(const float* __restrict__ emb,
                           const float* __restrict__ cs,
                           const float* __restrict__ cnorm,
                           const float* __restrict__ bscore,
                           const int* __restrict__ bnn,
                           const int* __restrict__ bpatch,
                           float* __restrict__ out) {
    int b = blockIdx.x;
    int tid = threadIdx.x;  // 256
    __shared__ float q[D_DIM];    // nn_sample
    __shared__ float mf[D_DIM];   // max patch feature
    __shared__ float lv[256][KNN];
    __shared__ int   li[256][KNN];
    __shared__ float dsup[KNN];

    int nn = bnn[b];
    int mp = bpatch[b];
    const float* frow = emb + (size_t)(b * P_PATCH + mp) * D_DIM;
    for (int i = tid; i < D_DIM; i += 256) {
        q[i]  = cs[(size_t)nn * D_DIM + i];
        mf[i] = frow[i];
    }
    __syncthreads();

    // local top-9 by (dist^2 proxy, index)
    float tv[KNN]; int ti[KNN];
#pragma unroll
    for (int k = 0; k < KNN; ++k) { tv[k] = 3.4e38f; ti[k] = 0x7fffffff; }
    for (int n = tid; n < N_CS; n += 256) {
        const float* r = cs + (size_t)n * D_DIM;
        float s = 0.f;
        for (int i = 0; i < D_DIM; i += 4) {
            float4 v = *(const float4*)&r[i];
            s += v.x * q[i] + v.y * q[i + 1] + v.z * q[i + 2] + v.w * q[i + 3];
        }
        float d = cnorm[n] - 2.f * s;   // qnorm omitted: constant shift
        if (d < tv[KNN - 1] || (d == tv[KNN - 1] && n < ti[KNN - 1])) {
            tv[KNN - 1] = d; ti[KNN - 1] = n;
#pragma unroll
            for (int k = KNN - 1; k > 0; --k) {
                if (tv[k] < tv[k - 1] || (tv[k] == tv[k - 1] && ti[k] < ti[k - 1])) {
                    float fv = tv[k]; tv[k] = tv[k - 1]; tv[k - 1] = fv;
                    int   iv = ti[k]; ti[k] = ti[k - 1]; ti[k - 1] = iv;
                }
            }
        }
    }
#pragma unroll
    for (int k = 0; k < KNN; ++k) { lv[tid][k] = tv[k]; li[tid][k] = ti[k]; }
    __syncthreads();
    for (int off = 128; off > 0; off >>= 1) {
        if (tid < off) {
            float av[KNN]; int ai[KNN]; float bv2[KNN]; int bi2[KNN];
#pragma unroll
            for (int k = 0; k < KNN; ++k) {
                av[k]  = lv[tid][k];        ai[k]  = li[tid][k];
                bv2[k] = lv[tid + off][k];  bi2[k] = li[tid + off][k];
            }
            merge9(av, ai, bv2, bi2);
#pragma unroll
            for (int k = 0; k < KNN; ++k) { lv[tid][k] = av[k]; li[tid][k] = ai[k]; }
        }
        __syncthreads();
    }

    // distances from max patch feature to the 9 support samples (exact form)
    if (tid < KNN) {
        int idx = li[0][tid];
        const float* r = cs + (size_t)idx * D_DIM;
        float s = 0.f;
        for (int i = 0; i < D_DIM; ++i) {
            float df = mf[i] - r[i];
            s += df * df;
        }
        dsup[tid] = sqrtf(fmaxf(s, 0.f));
    }
    __syncthreads();
    if (tid == 0) {
        float mx = dsup[0];
        for (int k = 1; k < KNN; ++k) mx = fmaxf(mx, dsup[k]);
        float sum = 0.f, e0 = 0.f;
        for (int k = 0; k < KNN; ++k) {
            float e = expf(dsup[k] - mx);
            sum += e;
            if (k == 0) e0 = e;
        }
        out[b] = (1.f - e0 / sum) * bscore[b];
    }
}

// ------------------------------------------------------------- launcher ----
extern "C" void kernel_launch(void* const* d_in, const int* in_sizes, int n_in,
                              void* d_out, int out_size, void* d_ws, size_t ws_size,
                              hipStream_t stream) {
    (void)in_sizes; (void)n_in; (void)out_size; (void)ws_size;
    const float* emb = (const float*)d_in[0];
    const float* cs  = (const float*)d_in[1];
    float* out = (float*)d_out;

    // workspace layout
    float* cnorm  = (float*)d_ws;                          // N_CS
    float* pnorm  = cnorm + N_CS;                          // M_TOTAL
    float* pvals  = pnorm + M_TOTAL;                       // M_TOTAL*NC
    int*   pidx   = (int*)(pvals + (size_t)M_TOTAL * NC);  // M_TOTAL*NC
    float* scores = (float*)(pidx + (size_t)M_TOTAL * NC); // M_TOTAL
    int*   loc    = (int*)(scores + M_TOTAL);              // M_TOTAL
    float* bscore = (float*)(loc + M_TOTAL);               // BATCH
    int*   bpatch = (int*)(bscore + BATCH);                // BATCH
    int*   bnn    = bpatch + BATCH;                        // BATCH

    {
        int waves = M_TOTAL + N_CS;
        int blocks = (waves * 64 + 255) / 256;
        norms_kernel<<<blocks, 256, 0, stream>>>(emb, cs, pnorm, cnorm);
    }
    {
        dim3 grid(M_TOTAL / MT, NC);
        mindist_kernel<<<grid, 256, 0, stream>>>(emb, cs, cnorm, pvals, pidx);
    }
    {
        int blocks = (M_TOTAL + 255) / 256;
        reduce_kernel<<<blocks, 256, 0, stream>>>(pvals, pidx, pnorm, scores, loc);
    }
    argmax_kernel<<<BATCH, 256, 0, stream>>>(scores, loc, bscore, bnn, bpatch);
    knn_kernel<<<BATCH, 256, 0, stream>>>(emb, cs, cnorm, bscore, bnn, bpatch, out);
}

// Round 2
// 1680.542 us; speedup vs baseline: 4.1618x; 4.1618x over previous
//
#include <hip/hip_runtime.h>
#include <hip/hip_bf16.h>
#include <math.h>

// Problem constants (fixed by setup_inputs)
#define M_TOTAL 6272   // B*P
#define N_CS    16384  // coreset rows
#define D_DIM   384
#define BATCH   8
#define P_PATCH 784
#define KNN     9

// GEMM tiling
#define NC    32            // coreset chunks (grid.y)
#define CHUNK (N_CS / NC)   // 512
#define MT    128
#define NT    128
#define BK    32
#define LDSS  (MT + 4)      // 132 floats: keeps float4 alignment, modest conflicts

// knn pass
#define KSLICES 32
#define KROWS   (N_CS / KSLICES)  // 512

// ---------------------------------------------------------------- norms ----
__global__ void norms_kernel(const float* __restrict__ emb,
                             const float* __restrict__ cs,
                             float* __restrict__ pnorm,
                             float* __restrict__ cnorm) {
    int gw   = (blockIdx.x * blockDim.x + threadIdx.x) >> 6;
    int lane = threadIdx.x & 63;
    if (gw >= M_TOTAL + N_CS) return;
    const float* row = (gw < N_CS) ? cs + (size_t)gw * D_DIM
                                   : emb + (size_t)(gw - N_CS) * D_DIM;
    float s = 0.f;
#pragma unroll
    for (int i = 0; i < D_DIM / 64; ++i) {
        float v = row[lane + i * 64];
        s += v * v;
    }
#pragma unroll
    for (int off = 32; off > 0; off >>= 1) s += __shfl_down(s, off, 64);
    if (lane == 0) {
        if (gw < N_CS) cnorm[gw] = s;
        else           pnorm[gw - N_CS] = s;
    }
}

// ------------------------------------------------- fused GEMM + min/argmin -
// block = 256 threads (16x16), 8x8 microtile -> 128x128 output tile.
// __launch_bounds__(256,2): VGPR cap 256 — R1 lesson: (256,4) capped at 64
// VGPRs and spilled the 64-reg acc tile -> 22 GB scratch traffic, 6.3 ms.
__global__ __launch_bounds__(256, 2) void mindist_kernel(
    const float* __restrict__ emb, const float* __restrict__ cs,
    const float* __restrict__ cnorm,
    float* __restrict__ pvals, int* __restrict__ pidx) {
    __shared__ float As[BK][LDSS];
    __shared__ float Bs[BK][LDSS];

    const int tid  = threadIdx.x;
    const int tx   = tid & 15;    // col group
    const int ty   = tid >> 4;    // row group
    const int row0 = blockIdx.x * MT;
    const int chunk = blockIdx.y;
    const int cbase0 = chunk * CHUNK;

    // loader mapping: 8 threads cover 32 consecutive k-floats of one row
    const int kg = tid & 7;
    const int m0 = tid >> 3;   // 0..31, rows m0 + 32*q

    float minv[8];
    int   mini[8];
#pragma unroll
    for (int i = 0; i < 8; ++i) { minv[i] = 3.4e38f; mini[i] = 0; }

    for (int it = 0; it < CHUNK / NT; ++it) {
        const int cbase = cbase0 + it * NT;

        float acc[8][8];
#pragma unroll
        for (int i = 0; i < 8; ++i)
#pragma unroll
            for (int j = 0; j < 8; ++j) acc[i][j] = 0.f;

        float cn[8];
#pragma unroll
        for (int j = 0; j < 8; ++j) cn[j] = cnorm[cbase + tx * 8 + j];

        for (int kk = 0; kk < D_DIM; kk += BK) {
            __syncthreads();
#pragma unroll
            for (int q = 0; q < 4; ++q) {
                int m = m0 + 32 * q;
                float4 av = *(const float4*)&emb[(size_t)(row0 + m) * D_DIM + kk + kg * 4];
                As[kg * 4 + 0][m] = av.x; As[kg * 4 + 1][m] = av.y;
                As[kg * 4 + 2][m] = av.z; As[kg * 4 + 3][m] = av.w;
                float4 bv = *(const float4*)&cs[(size_t)(cbase + m) * D_DIM + kk + kg * 4];
                Bs[kg * 4 + 0][m] = bv.x; Bs[kg * 4 + 1][m] = bv.y;
                Bs[kg * 4 + 2][m] = bv.z; Bs[kg * 4 + 3][m] = bv.w;
            }
            __syncthreads();
#pragma unroll
            for (int k = 0; k < BK; ++k) {
                float4 a0 = *(const float4*)&As[k][ty * 8];
                float4 a1 = *(const float4*)&As[k][ty * 8 + 4];
                float4 b0 = *(const float4*)&Bs[k][tx * 8];
                float4 b1 = *(const float4*)&Bs[k][tx * 8 + 4];
                float a[8] = {a0.x, a0.y, a0.z, a0.w, a1.x, a1.y, a1.z, a1.w};
                float b[8] = {b0.x, b0.y, b0.z, b0.w, b1.x, b1.y, b1.z, b1.w};
#pragma unroll
                for (int i = 0; i < 8; ++i)
#pragma unroll
                    for (int j = 0; j < 8; ++j) acc[i][j] += a[i] * b[j];
            }
        }
        // fold into running min (visit order = ascending col index per thread)
#pragma unroll
        for (int i = 0; i < 8; ++i) {
#pragma unroll
            for (int j = 0; j < 8; ++j) {
                float d = cn[j] - 2.f * acc[i][j];   // dist^2 - pnorm (monotone)
                int   c = cbase + tx * 8 + j;
                if (d < minv[i]) { minv[i] = d; mini[i] = c; }
            }
        }
    }

    // cross-tx reduction per row (reuse As/Bs as scratch)
    __syncthreads();
    float* redv = &As[0][0];
    int*   redi = (int*)&Bs[0][0];
#pragma unroll
    for (int i = 0; i < 8; ++i) {
        int r = ty * 8 + i;
        redv[r * 16 + tx] = minv[i];
        redi[r * 16 + tx] = mini[i];
    }
    __syncthreads();
    if (tid < 128) {
        int r = tid;
        float bv = redv[r * 16];
        int   bi = redi[r * 16];
        for (int x = 1; x < 16; ++x) {
            float v = redv[r * 16 + x];
            int  ii = redi[r * 16 + x];
            if (v < bv || (v == bv && ii < bi)) { bv = v; bi = ii; }
        }
        pvals[(size_t)(row0 + r) * NC + chunk] = bv;
        pidx[(row0 + r) * NC + chunk] = bi;
    }
}

// ------------------------------------------- partial-min reduce + score ----
__global__ void reduce_kernel(const float* __restrict__ pvals,
                              const int* __restrict__ pidx,
                              const float* __restrict__ pnorm,
                              float* __restrict__ scores, int* __restrict__ loc) {
    int m = blockIdx.x * blockDim.x + threadIdx.x;
    if (m >= M_TOTAL) return;
    float bv = pvals[(size_t)m * NC];
    int   bi = pidx[(size_t)m * NC];
    for (int c = 1; c < NC; ++c) {
        float v = pvals[(size_t)m * NC + c];
        int  ii = pidx[(size_t)m * NC + c];
        if (v < bv || (v == bv && ii < bi)) { bv = v; bi = ii; }
    }
    scores[m] = sqrtf(fmaxf(pnorm[m] + bv, 0.f));
    loc[m] = bi;
}

// ---------------------------------------------------- per-batch argmax ----
__global__ void argmax_kernel(const float* __restrict__ scores,
                              const int* __restrict__ loc,
                              float* __restrict__ bscore,
                              int* __restrict__ bnn, int* __restrict__ bpatch) {
    int b = blockIdx.x;
    int tid = threadIdx.x;
    float bv = -1.f;
    int bp = 0x7fffffff;
    for (int p = tid; p < P_PATCH; p += 256) {
        float v = scores[b * P_PATCH + p];
        if (v > bv || (v == bv && p < bp)) { bv = v; bp = p; }
    }
    __shared__ float sv[256];
    __shared__ int   sp[256];
    sv[tid] = bv; sp[tid] = bp;
    __syncthreads();
    for (int off = 128; off > 0; off >>= 1) {
        if (tid < off) {
            float v = sv[tid + off]; int p = sp[tid + off];
            if (v > sv[tid] || (v == sv[tid] && p < sp[tid])) { sv[tid] = v; sp[tid] = p; }
        }
        __syncthreads();
    }
    if (tid == 0) {
        bscore[b] = sv[0];
        bpatch[b] = sp[0];
        bnn[b]    = loc[b * P_PATCH + sp[0]];
    }
}

// --------------------------------- 9-NN in coreset (partial, 32 slices) ----
__device__ inline void merge9(float* av, int* ai, const float* bv, const int* bi) {
    float mv[KNN]; int mi[KNN];
    int x = 0, y = 0;
#pragma unroll
    for (int k = 0; k < KNN; ++k) {
        bool ta = (av[x] < bv[y]) || (av[x] == bv[y] && ai[x] < bi[y]);
        if (ta) { mv[k] = av[x]; mi[k] = ai[x]; ++x; }
        else    { mv[k] = bv[y]; mi[k] = bi[y]; ++y; }
    }
#pragma unroll
    for (int k = 0; k < KNN; ++k) { av[k] = mv[k]; ai[k] = mi[k]; }
}

__global__ void knn_partial_kernel(const float* __restrict__ cs,
                                   const float* __restrict__ cnorm,
                                   const int* __restrict__ bnn,
                                   float* __restrict__ kvals,
                                   int* __restrict__ kidx) {
    int b     = blockIdx.x >> 5;
    int slice = blockIdx.x & 31;
    int tid   = threadIdx.x;  // 256
    __shared__ float q[D_DIM];
    __shared__ float lv[256][KNN];
    __shared__ int   li[256][KNN];

    int nn = bnn[b];
    for (int i = tid; i < D_DIM; i += 256) q[i] = cs[(size_t)nn * D_DIM + i];
    __syncthreads();

    float tv[KNN]; int ti[KNN];
#pragma unroll
    for (int k = 0; k < KNN; ++k) { tv[k] = 3.4e38f; ti[k] = 0x7fffffff; }
    int base = slice * KROWS;
    for (int n = base + tid; n < base + KROWS; n += 256) {
        const float* r = cs + (size_t)n * D_DIM;
        float s = 0.f;
        for (int i = 0; i < D_DIM; i += 4) {
            float4 v = *(const float4*)&r[i];
            s += v.x * q[i] + v.y * q[i + 1] + v.z * q[i + 2] + v.w * q[i + 3];
        }
        float d = cnorm[n] - 2.f * s;   // qnorm omitted: constant shift
        if (d < tv[KNN - 1] || (d == tv[KNN - 1] && n < ti[KNN - 1])) {
            tv[KNN - 1] = d; ti[KNN - 1] = n;
#pragma unroll
            for (int k = KNN - 1; k > 0; --k) {
                if (tv[k] < tv[k - 1] || (tv[k] == tv[k - 1] && ti[k] < ti[k - 1])) {
                    float fv = tv[k]; tv[k] = tv[k - 1]; tv[k - 1] = fv;
                    int   iv = ti[k]; ti[k] = ti[k - 1]; ti[k - 1] = iv;
                }
            }
        }
    }
#pragma unroll
    for (int k = 0; k < KNN; ++k) { lv[tid][k] = tv[k]; li[tid][k] = ti[k]; }
    __syncthreads();
    for (int off = 128; off > 0; off >>= 1) {
        if (tid < off) {
            float av[KNN]; int ai[KNN]; float bv2[KNN]; int bi2[KNN];
#pragma unroll
            for (int k = 0; k < KNN; ++k) {
                av[k]  = lv[tid][k];        ai[k]  = li[tid][k];
                bv2[k] = lv[tid + off][k];  bi2[k] = li[tid + off][k];
            }
            merge9(av, ai, bv2, bi2);
#pragma unroll
            for (int k = 0; k < KNN; ++k) { lv[tid][k] = av[k]; li[tid][k] = ai[k]; }
        }
        __syncthreads();
    }
    if (tid < KNN) {
        kvals[(b * KSLICES + slice) * KNN + tid] = lv[0][tid];
        kidx[(b * KSLICES + slice) * KNN + tid]  = li[0][tid];
    }
}

// ----------------------------------- final merge + softmax weighting ----
__global__ void knn_final_kernel(const float* __restrict__ emb,
                                 const float* __restrict__ cs,
                                 const float* __restrict__ kvals,
                                 const int* __restrict__ kidx,
                                 const float* __restrict__ bscore,
                                 const int* __restrict__ bpatch,
                                 float* __restrict__ out) {
    int b = blockIdx.x;
    int tid = threadIdx.x;  // 256
    const int NCAND = KSLICES * KNN;  // 288
    __shared__ float cv[NCAND];
    __shared__ int   ci[NCAND];
    __shared__ float mf[D_DIM];
    __shared__ int   sel[KNN];
    __shared__ float dsup[KNN];

    for (int i = tid; i < NCAND; i += 256) {
        cv[i] = kvals[b * NCAND + i];
        ci[i] = kidx[b * NCAND + i];
    }
    int mp = bpatch[b];
    const float* frow = emb + (size_t)(b * P_PATCH + mp) * D_DIM;
    for (int i = tid; i < D_DIM; i += 256) mf[i] = frow[i];
    __syncthreads();

    if (tid == 0) {
        for (int k = 0; k < KNN; ++k) {
            float bv = 3.4e38f; int bi = 0x7fffffff; int bj = -1;
            for (int j = 0; j < NCAND; ++j) {
                if (cv[j] < bv || (cv[j] == bv && ci[j] < bi)) { bv = cv[j]; bi = ci[j]; bj = j; }
            }
            sel[k] = bi;
            cv[bj] = 3.4e38f; ci[bj] = 0x7fffffff;
        }
    }
    __syncthreads();
    if (tid < KNN) {
        int idx = sel[tid];
        const float* r = cs + (size_t)idx * D_DIM;
        float s = 0.f;
        for (int i = 0; i < D_DIM; ++i) {
            float df = mf[i] - r[i];
            s += df * df;
        }
        dsup[tid] = sqrtf(fmaxf(s, 0.f));
    }
    __syncthreads();
    if (tid == 0) {
        float mx = dsup[0];
        for (int k = 1; k < KNN; ++k) mx = fmaxf(mx, dsup[k]);
        float sum = 0.f, e0 = 0.f;
        for (int k = 0; k < KNN; ++k) {
            float e = expf(dsup[k] - mx);
            sum += e;
            if (k == 0) e0 = e;
        }
        out[b] = (1.f - e0 / sum) * bscore[b];
    }
}

// ------------------------------------------------------------- launcher ----
extern "C" void kernel_launch(void* const* d_in, const int* in_sizes, int n_in,
                              void* d_out, int out_size, void* d_ws, size_t ws_size,
                              hipStream_t stream) {
    (void)in_sizes; (void)n_in; (void)out_size; (void)ws_size;
    const float* emb = (const float*)d_in[0];
    const float* cs  = (const float*)d_in[1];
    float* out = (float*)d_out;

    // workspace layout
    float* cnorm  = (float*)d_ws;                          // N_CS
    float* pnorm  = cnorm + N_CS;                          // M_TOTAL
    float* pvals  = pnorm + M_TOTAL;                       // M_TOTAL*NC
    int*   pidx   = (int*)(pvals + (size_t)M_TOTAL * NC);  // M_TOTAL*NC
    float* scores = (float*)(pidx + (size_t)M_TOTAL * NC); // M_TOTAL
    int*   loc    = (int*)(scores + M_TOTAL);              // M_TOTAL
    float* bscore = (float*)(loc + M_TOTAL);               // BATCH
    int*   bpatch = (int*)(bscore + BATCH);                // BATCH
    int*   bnn    = bpatch + BATCH;                        // BATCH
    float* kvals  = (float*)(bnn + BATCH);                 // BATCH*KSLICES*KNN
    int*   kidx   = (int*)(kvals + BATCH * KSLICES * KNN); // BATCH*KSLICES*KNN

    {
        int waves = M_TOTAL + N_CS;
        int blocks = (waves * 64 + 255) / 256;
        norms_kernel<<<blocks, 256, 0, stream>>>(emb, cs, pnorm, cnorm);
    }
    {
        dim3 grid(M_TOTAL / MT, NC);
        mindist_kernel<<<grid, 256, 0, stream>>>(emb, cs, cnorm, pvals, pidx);
    }
    {
        int blocks = (M_TOTAL + 255) / 256;
        reduce_kernel<<<blocks, 256, 0, stream>>>(pvals, pidx, pnorm, scores, loc);
    }
    argmax_kernel<<<BATCH, 256, 0, stream>>>(scores, loc, bscore, bnn, bpatch);
    knn_partial_kernel<<<BATCH * KSLICES, 256, 0, stream>>>(cs, cnorm, bnn, kvals, kidx);
    knn_final_kernel<<<BATCH, 256, 0, stream>>>(emb, cs, kvals, kidx, bscore, bpatch, out);
}

// Round 3
// 541.219 us; speedup vs baseline: 12.9229x; 3.1051x over previous
//
#include <hip/hip_runtime.h>
#include <hip/hip_bf16.h>
#include <math.h>

// Problem constants (fixed by setup_inputs)
#define M_TOTAL 6272   // B*P
#define N_CS    16384  // coreset rows
#define D_DIM   384
#define BATCH   8
#define P_PATCH 784
#define KNN     9

// MFMA GEMM tiling: 128x128 tile, 4 waves (2x2 of 64x64), BK=64
#define NTILES  (N_CS / 128)   // 128 N-chunks -> pvals[m][128]
#define MTILES  (M_TOTAL / 128) // 49

// knn pass
#define KSLICES 32
#define KROWS   (N_CS / KSLICES)  // 512

typedef _Float16 half8 __attribute__((ext_vector_type(8)));
typedef float    floatx4 __attribute__((ext_vector_type(4)));

// async global->LDS, 16B per lane; LDS dest must be uniform-base + lane*16
__device__ __forceinline__ void async_copy16(const void* g, void* l) {
    __builtin_amdgcn_global_load_lds(
        (const __attribute__((address_space(1))) void*)g,
        (__attribute__((address_space(3))) void*)l, 16, 0, 0);
}

// ------------------------------------------------------------ convert ----
// fp32 -> f16 rows (hi only; MFMA accumulates fp32, input rounding ~2^-11)
__global__ void convert_kernel(const float* __restrict__ in,
                               _Float16* __restrict__ out, int n8) {
    int t = blockIdx.x * 256 + threadIdx.x;
    if (t >= n8) return;
    const float4* p = (const float4*)in + (size_t)t * 2;
    float4 x = p[0], y = p[1];
    half8 h = { (_Float16)x.x, (_Float16)x.y, (_Float16)x.z, (_Float16)x.w,
                (_Float16)y.x, (_Float16)y.y, (_Float16)y.z, (_Float16)y.w };
    *(half8*)(out + (size_t)t * 8) = h;
}

// ------------------------------------------------------------- cnorm ----
__global__ void cnorm_kernel(const float* __restrict__ cs,
                             float* __restrict__ cnorm) {
    int gw   = (blockIdx.x * 256 + threadIdx.x) >> 6;
    int lane = threadIdx.x & 63;
    if (gw >= N_CS) return;
    const float* row = cs + (size_t)gw * D_DIM;
    float s = 0.f;
#pragma unroll
    for (int i = 0; i < D_DIM / 64; ++i) {
        float v = row[lane + i * 64];
        s += v * v;
    }
#pragma unroll
    for (int off = 32; off > 0; off >>= 1) s += __shfl_down(s, off, 64);
    if (lane == 0) cnorm[gw] = s;
}

// --------------------------------------------- MFMA GEMM + min/argmin ----
// grid (49, 128); block 256 = 4 waves in 2x2 of 64x64 subtiles.
// Fragment layout (16x16x32): A/B lane holds 8 consecutive k of row (lane&15)
// at k-offset (lane>>4)*8; C/D: col=lane&15, row=(lane>>4)*4+reg.
__global__ __launch_bounds__(256, 2) void mindist_mfma_kernel(
    const _Float16* __restrict__ embh, const _Float16* __restrict__ csh,
    const float* __restrict__ cnorm,
    float* __restrict__ pvals, int* __restrict__ pidx) {
    __shared__ _Float16 As[128 * 64];   // [row][k] row-major, no padding (lds-dma)
    __shared__ _Float16 Bs[128 * 64];

    const int tid  = threadIdx.x;
    const int lane = tid & 63;
    const int w    = tid >> 6;
    const int wr   = w >> 1, wc = w & 1;
    const int row0  = blockIdx.x * 128;
    const int cbase = blockIdx.y * 128;
    const int q  = lane >> 4;
    const int cl = lane & 15;

    floatx4 acc[4][4];
#pragma unroll
    for (int mi = 0; mi < 4; ++mi)
#pragma unroll
        for (int nj = 0; nj < 4; ++nj) acc[mi][nj] = (floatx4){0.f, 0.f, 0.f, 0.f};

    float cn_l[4];
#pragma unroll
    for (int nj = 0; nj < 4; ++nj)
        cn_l[nj] = cnorm[cbase + wc * 64 + nj * 16 + cl];

    for (int kk = 0; kk < D_DIM; kk += 64) {
        __syncthreads();
#pragma unroll
        for (int i = 0; i < 4; ++i) {
            int inst = w * 4 + i;           // 0..15, each stages 8 rows x 128B
            int r    = inst * 8 + (lane >> 3);
            int kb   = (lane & 7) * 8;      // element offset (16B per lane)
            async_copy16(embh + (size_t)(row0 + r) * D_DIM + kk + kb,
                         &As[inst * 512 + lane * 8]);
            async_copy16(csh + (size_t)(cbase + r) * D_DIM + kk + kb,
                         &Bs[inst * 512 + lane * 8]);
        }
        __syncthreads();
#pragma unroll
        for (int ks = 0; ks < 64; ks += 32) {
            half8 af[4], bf[4];
#pragma unroll
            for (int mi = 0; mi < 4; ++mi)
                af[mi] = *(const half8*)&As[(wr * 64 + mi * 16 + cl) * 64 + ks + q * 8];
#pragma unroll
            for (int nj = 0; nj < 4; ++nj)
                bf[nj] = *(const half8*)&Bs[(wc * 64 + nj * 16 + cl) * 64 + ks + q * 8];
#pragma unroll
            for (int mi = 0; mi < 4; ++mi)
#pragma unroll
                for (int nj = 0; nj < 4; ++nj)
                    acc[mi][nj] = __builtin_amdgcn_mfma_f32_16x16x32_f16(
                        af[mi], bf[nj], acc[mi][nj], 0, 0, 0);
        }
    }

    __syncthreads();
    float* smv = (float*)As;            // [128][2]
    int*   smi = (int*)(As + 2048);     // [128][2] (4KB past smv)

#pragma unroll
    for (int mi = 0; mi < 4; ++mi) {
#pragma unroll
        for (int r = 0; r < 4; ++r) {
            float v = 3.4e38f; int idx = 0x7fffffff;
#pragma unroll
            for (int nj = 0; nj < 4; ++nj) {   // ascending col, strict <
                float d = cn_l[nj] - 2.f * acc[mi][nj][r];
                int   c = cbase + wc * 64 + nj * 16 + cl;
                if (d < v) { v = d; idx = c; }
            }
#pragma unroll
            for (int mk = 1; mk <= 8; mk <<= 1) {
                float v2 = __shfl_xor(v, mk, 64);
                int   i2 = __shfl_xor(idx, mk, 64);
                if (v2 < v || (v2 == v && i2 < idx)) { v = v2; idx = i2; }
            }
            if (cl == 0) {
                int rl = wr * 64 + mi * 16 + q * 4 + r;
                smv[rl * 2 + wc] = v;
                smi[rl * 2 + wc] = idx;
            }
        }
    }
    __syncthreads();
    if (tid < 128) {
        float v = smv[tid * 2];  int i = smi[tid * 2];
        float v1 = smv[tid * 2 + 1]; int i1 = smi[tid * 2 + 1];
        if (v1 < v) { v = v1; i = i1; }   // wc0 indices always < wc1 indices
        pvals[(size_t)(row0 + tid) * NTILES + blockIdx.y] = v;
        pidx[(size_t)(row0 + tid) * NTILES + blockIdx.y]  = i;
    }
}

// ------------------------- partial-min reduce + EXACT fp32 rescore ----
// one wave per patch row; chunk order ascending = index ascending
__global__ void reduce_rescore_kernel(const float* __restrict__ pvals,
                                      const int* __restrict__ pidx,
                                      const float* __restrict__ emb,
                                      const float* __restrict__ cs,
                                      float* __restrict__ scores,
                                      int* __restrict__ loc) {
    int w = threadIdx.x >> 6, lane = threadIdx.x & 63;
    int m = blockIdx.x * 4 + w;
    float v = pvals[(size_t)m * NTILES + lane];
    int   i = pidx[(size_t)m * NTILES + lane];
    float v1 = pvals[(size_t)m * NTILES + 64 + lane];
    int   i1 = pidx[(size_t)m * NTILES + 64 + lane];
    if (v1 < v || (v1 == v && i1 < i)) { v = v1; i = i1; }
#pragma unroll
    for (int mk = 1; mk <= 32; mk <<= 1) {
        float v2 = __shfl_xor(v, mk, 64);
        int   i2 = __shfl_xor(i, mk, 64);
        if (v2 < v || (v2 == v && i2 < i)) { v = v2; i = i2; }
    }
    // exact fp32 distance to the selected coreset row
    const float* a = emb + (size_t)m * D_DIM;
    const float* b = cs + (size_t)i * D_DIM;
    float s = 0.f;
#pragma unroll
    for (int t = 0; t < D_DIM / 64; ++t) {
        float d = a[lane + t * 64] - b[lane + t * 64];
        s += d * d;
    }
#pragma unroll
    for (int mk = 1; mk <= 32; mk <<= 1) s += __shfl_xor(s, mk, 64);
    if (lane == 0) { scores[m] = sqrtf(s); loc[m] = i; }
}

// ---------------------------------------------------- per-batch argmax ----
__global__ void argmax_kernel(const float* __restrict__ scores,
                              const int* __restrict__ loc,
                              float* __restrict__ bscore,
                              int* __restrict__ bnn, int* __restrict__ bpatch) {
    int b = blockIdx.x;
    int tid = threadIdx.x;
    float bv = -1.f;
    int bp = 0x7fffffff;
    for (int p = tid; p < P_PATCH; p += 256) {
        float v = scores[b * P_PATCH + p];
        if (v > bv || (v == bv && p < bp)) { bv = v; bp = p; }
    }
    __shared__ float sv[256];
    __shared__ int   sp[256];
    sv[tid] = bv; sp[tid] = bp;
    __syncthreads();
    for (int off = 128; off > 0; off >>= 1) {
        if (tid < off) {
            float v = sv[tid + off]; int p = sp[tid + off];
            if (v > sv[tid] || (v == sv[tid] && p < sp[tid])) { sv[tid] = v; sp[tid] = p; }
        }
        __syncthreads();
    }
    if (tid == 0) {
        bscore[b] = sv[0];
        bpatch[b] = sp[0];
        bnn[b]    = loc[b * P_PATCH + sp[0]];
    }
}

// --------------------------------- 9-NN in coreset (partial, 32 slices) ----
__device__ inline void merge9(float* av, int* ai, const float* bv, const int* bi) {
    float mv[KNN]; int mi[KNN];
    int x = 0, y = 0;
#pragma unroll
    for (int k = 0; k < KNN; ++k) {
        bool ta = (av[x] < bv[y]) || (av[x] == bv[y] && ai[x] < bi[y]);
        if (ta) { mv[k] = av[x]; mi[k] = ai[x]; ++x; }
        else    { mv[k] = bv[y]; mi[k] = bi[y]; ++y; }
    }
#pragma unroll
    for (int k = 0; k < KNN; ++k) { av[k] = mv[k]; ai[k] = mi[k]; }
}

__global__ void knn_partial_kernel(const float* __restrict__ cs,
                                   const float* __restrict__ cnorm,
                                   const int* __restrict__ bnn,
                                   float* __restrict__ kvals,
                                   int* __restrict__ kidx) {
    int b     = blockIdx.x >> 5;
    int slice = blockIdx.x & 31;
    int tid   = threadIdx.x;  // 256
    __shared__ float q[D_DIM];
    __shared__ float lv[256][KNN];
    __shared__ int   li[256][KNN];

    int nn = bnn[b];
    for (int i = tid; i < D_DIM; i += 256) q[i] = cs[(size_t)nn * D_DIM + i];
    __syncthreads();

    float tv[KNN]; int ti[KNN];
#pragma unroll
    for (int k = 0; k < KNN; ++k) { tv[k] = 3.4e38f; ti[k] = 0x7fffffff; }
    int base = slice * KROWS;
    for (int n = base + tid; n < base + KROWS; n += 256) {
        const float* r = cs + (size_t)n * D_DIM;
        float s = 0.f;
        for (int i = 0; i < D_DIM; i += 4) {
            float4 v = *(const float4*)&r[i];
            s += v.x * q[i] + v.y * q[i + 1] + v.z * q[i + 2] + v.w * q[i + 3];
        }
        float d = cnorm[n] - 2.f * s;   // qnorm omitted: constant shift
        if (d < tv[KNN - 1] || (d == tv[KNN - 1] && n < ti[KNN - 1])) {
            tv[KNN - 1] = d; ti[KNN - 1] = n;
#pragma unroll
            for (int k = KNN - 1; k > 0; --k) {
                if (tv[k] < tv[k - 1] || (tv[k] == tv[k - 1] && ti[k] < ti[k - 1])) {
                    float fv = tv[k]; tv[k] = tv[k - 1]; tv[k - 1] = fv;
                    int   iv = ti[k]; ti[k] = ti[k - 1]; ti[k - 1] = iv;
                }
            }
        }
    }
#pragma unroll
    for (int k = 0; k < KNN; ++k) { lv[tid][k] = tv[k]; li[tid][k] = ti[k]; }
    __syncthreads();
    for (int off = 128; off > 0; off >>= 1) {
        if (tid < off) {
            float av[KNN]; int ai[KNN]; float bv2[KNN]; int bi2[KNN];
#pragma unroll
            for (int k = 0; k < KNN; ++k) {
                av[k]  = lv[tid][k];        ai[k]  = li[tid][k];
                bv2[k] = lv[tid + off][k];  bi2[k] = li[tid + off][k];
            }
            merge9(av, ai, bv2, bi2);
#pragma unroll
            for (int k = 0; k < KNN; ++k) { lv[tid][k] = av[k]; li[tid][k] = ai[k]; }
        }
        __syncthreads();
    }
    if (tid < KNN) {
        kvals[(b * KSLICES + slice) * KNN + tid] = lv[0][tid];
        kidx[(b * KSLICES + slice) * KNN + tid]  = li[0][tid];
    }
}

// ----------------------------------- final merge + softmax weighting ----
__global__ void knn_final_kernel(const float* __restrict__ emb,
                                 const float* __restrict__ cs,
                                 const float* __restrict__ kvals,
                                 const int* __restrict__ kidx,
                                 const float* __restrict__ bscore,
                                 const int* __restrict__ bpatch,
                                 float* __restrict__ out) {
    int b = blockIdx.x;
    int tid = threadIdx.x;  // 256
    const int NCAND = KSLICES * KNN;  // 288
    __shared__ float cv[NCAND];
    __shared__ int   ci[NCAND];
    __shared__ float mf[D_DIM];
    __shared__ int   sel[KNN];
    __shared__ float dsup[KNN];

    for (int i = tid; i < NCAND; i += 256) {
        cv[i] = kvals[b * NCAND + i];
        ci[i] = kidx[b * NCAND + i];
    }
    int mp = bpatch[b];
    const float* frow = emb + (size_t)(b * P_PATCH + mp) * D_DIM;
    for (int i = tid; i < D_DIM; i += 256) mf[i] = frow[i];
    __syncthreads();

    if (tid == 0) {
        for (int k = 0; k < KNN; ++k) {
            float bv = 3.4e38f; int bi = 0x7fffffff; int bj = -1;
            for (int j = 0; j < NCAND; ++j) {
                if (cv[j] < bv || (cv[j] == bv && ci[j] < bi)) { bv = cv[j]; bi = ci[j]; bj = j; }
            }
            sel[k] = bi;
            cv[bj] = 3.4e38f; ci[bj] = 0x7fffffff;
        }
    }
    __syncthreads();
    if (tid < KNN) {
        int idx = sel[tid];
        const float* r = cs + (size_t)idx * D_DIM;
        float s = 0.f;
        for (int i = 0; i < D_DIM; ++i) {
            float df = mf[i] - r[i];
            s += df * df;
        }
        dsup[tid] = sqrtf(fmaxf(s, 0.f));
    }
    __syncthreads();
    if (tid == 0) {
        float mx = dsup[0];
        for (int k = 1; k < KNN; ++k) mx = fmaxf(mx, dsup[k]);
        float sum = 0.f, e0 = 0.f;
        for (int k = 0; k < KNN; ++k) {
            float e = expf(dsup[k] - mx);
            sum += e;
            if (k == 0) e0 = e;
        }
        out[b] = (1.f - e0 / sum) * bscore[b];
    }
}

// ------------------------------------------------------------- launcher ----
extern "C" void kernel_launch(void* const* d_in, const int* in_sizes, int n_in,
                              void* d_out, int out_size, void* d_ws, size_t ws_size,
                              hipStream_t stream) {
    (void)in_sizes; (void)n_in; (void)out_size; (void)ws_size;
    const float* emb = (const float*)d_in[0];
    const float* cs  = (const float*)d_in[1];
    float* out = (float*)d_out;

    // workspace layout (bytes)
    char* p = (char*)d_ws;
    float* cnorm  = (float*)p;  p += (size_t)N_CS * 4;                    // 64 KB
    float* pvals  = (float*)p;  p += (size_t)M_TOTAL * NTILES * 4;       // 3.2 MB
    int*   pidx   = (int*)p;    p += (size_t)M_TOTAL * NTILES * 4;       // 3.2 MB
    float* scores = (float*)p;  p += (size_t)M_TOTAL * 4;
    int*   loc    = (int*)p;    p += (size_t)M_TOTAL * 4;
    float* bscore = (float*)p;  p += BATCH * 4;
    int*   bpatch = (int*)p;    p += BATCH * 4;
    int*   bnn    = (int*)p;    p += BATCH * 4;
    float* kvals  = (float*)p;  p += BATCH * KSLICES * KNN * 4;
    int*   kidx   = (int*)p;    p += BATCH * KSLICES * KNN * 4;
    p = (char*)(((size_t)p + 15) & ~(size_t)15);
    _Float16* embh = (_Float16*)p; p += (size_t)M_TOTAL * D_DIM * 2;     // 4.8 MB
    _Float16* csh  = (_Float16*)p; p += (size_t)N_CS * D_DIM * 2;        // 12.6 MB

    {
        int n8 = M_TOTAL * D_DIM / 8;
        convert_kernel<<<(n8 + 255) / 256, 256, 0, stream>>>(emb, embh, n8);
    }
    {
        int n8 = N_CS * D_DIM / 8;
        convert_kernel<<<(n8 + 255) / 256, 256, 0, stream>>>(cs, csh, n8);
    }
    cnorm_kernel<<<N_CS / 4, 256, 0, stream>>>(cs, cnorm);
    {
        dim3 grid(MTILES, NTILES);
        mindist_mfma_kernel<<<grid, 256, 0, stream>>>(embh, csh, cnorm, pvals, pidx);
    }
    reduce_rescore_kernel<<<M_TOTAL / 4, 256, 0, stream>>>(pvals, pidx, emb, cs, scores, loc);
    argmax_kernel<<<BATCH, 256, 0, stream>>>(scores, loc, bscore, bnn, bpatch);
    knn_partial_kernel<<<BATCH * KSLICES, 256, 0, stream>>>(cs, cnorm, bnn, kvals, kidx);
    knn_final_kernel<<<BATCH, 256, 0, stream>>>(emb, cs, kvals, kidx, bscore, bpatch, out);
}

// Round 4
// 335.759 us; speedup vs baseline: 20.8309x; 1.6119x over previous
//
#include <hip/hip_runtime.h>
#include <hip/hip_bf16.h>
#include <math.h>

// Problem constants (fixed by setup_inputs)
#define M_TOTAL 6272   // B*P
#define N_CS    16384  // coreset rows
#define D_DIM   384
#define BATCH   8
#define P_PATCH 784
#define KNN     9

// MFMA GEMM tiling: 128x256 tile, 4 waves (2x2 of 64x128), BK=64
#define MTILES  (M_TOTAL / 128)  // 49
#define NTILES2 (N_CS / 256)     // 64 -> pvals[m][64]

typedef _Float16 half8 __attribute__((ext_vector_type(8)));
typedef float    floatx4 __attribute__((ext_vector_type(4)));

// async global->LDS, 16B per lane; LDS dest must be uniform-base + lane*16
__device__ __forceinline__ void async_copy16(const void* g, void* l) {
    __builtin_amdgcn_global_load_lds(
        (const __attribute__((address_space(1))) void*)g,
        (__attribute__((address_space(3))) void*)l, 16, 0, 0);
}

// --------------------------- convert fp32->f16 (wave per row, coalesced) ----
// lane covers 6 consecutive floats: wave reads a contiguous 1536B row.
__global__ void convert_cs_kernel(const float* __restrict__ cs,
                                  _Float16* __restrict__ csh,
                                  float* __restrict__ cnorm) {
    int w = threadIdx.x >> 6, lane = threadIdx.x & 63;
    int row = blockIdx.x * 4 + w;
    const float* r = cs + (size_t)row * D_DIM + lane * 6;
    float2 a = *(const float2*)r;
    float2 b = *(const float2*)(r + 2);
    float2 c = *(const float2*)(r + 4);
    union { _Float16 h[2]; unsigned u; } p0, p1, p2;
    p0.h[0] = (_Float16)a.x; p0.h[1] = (_Float16)a.y;
    p1.h[0] = (_Float16)b.x; p1.h[1] = (_Float16)b.y;
    p2.h[0] = (_Float16)c.x; p2.h[1] = (_Float16)c.y;
    unsigned* dst = (unsigned*)(csh + (size_t)row * D_DIM) + lane * 3;
    dst[0] = p0.u; dst[1] = p1.u; dst[2] = p2.u;
    float s = a.x * a.x + a.y * a.y + b.x * b.x + b.y * b.y + c.x * c.x + c.y * c.y;
#pragma unroll
    for (int mk = 1; mk <= 32; mk <<= 1) s += __shfl_xor(s, mk, 64);
    if (lane == 0) cnorm[row] = s;
}

__global__ void convert_emb_kernel(const float* __restrict__ emb,
                                   _Float16* __restrict__ embh) {
    int w = threadIdx.x >> 6, lane = threadIdx.x & 63;
    int row = blockIdx.x * 4 + w;
    const float* r = emb + (size_t)row * D_DIM + lane * 6;
    float2 a = *(const float2*)r;
    float2 b = *(const float2*)(r + 2);
    float2 c = *(const float2*)(r + 4);
    union { _Float16 h[2]; unsigned u; } p0, p1, p2;
    p0.h[0] = (_Float16)a.x; p0.h[1] = (_Float16)a.y;
    p1.h[0] = (_Float16)b.x; p1.h[1] = (_Float16)b.y;
    p2.h[0] = (_Float16)c.x; p2.h[1] = (_Float16)c.y;
    unsigned* dst = (unsigned*)(embh + (size_t)row * D_DIM) + lane * 3;
    dst[0] = p0.u; dst[1] = p1.u; dst[2] = p2.u;
}

// --------------------------------------------- MFMA GEMM + min/argmin ----
// grid (49, 64); block 256 = 4 waves in 2x2 of 64x128 subtiles, BK=64.
// 128x256 tile: 2x MFMA per staging drain vs R3; epilogue once per 256 cols.
__global__ __launch_bounds__(256, 2) void mindist_mfma_kernel(
    const _Float16* __restrict__ embh, const _Float16* __restrict__ csh,
    const float* __restrict__ cnorm,
    float* __restrict__ pvals, int* __restrict__ pidx) {
    __shared__ _Float16 As[128 * 64];   // 16 KB, [row][k] contiguous (lds-dma)
    __shared__ _Float16 Bs[256 * 64];   // 32 KB

    const int tid  = threadIdx.x;
    const int lane = tid & 63;
    const int w    = tid >> 6;
    const int wr   = w >> 1, wc = w & 1;
    const int row0  = blockIdx.x * 128;
    const int cbase = blockIdx.y * 256;
    const int q  = lane >> 4;
    const int cl = lane & 15;

    floatx4 acc[4][8];
#pragma unroll
    for (int mi = 0; mi < 4; ++mi)
#pragma unroll
        for (int nj = 0; nj < 8; ++nj) acc[mi][nj] = (floatx4){0.f, 0.f, 0.f, 0.f};

    float cn_l[8];
#pragma unroll
    for (int nj = 0; nj < 8; ++nj)
        cn_l[nj] = cnorm[cbase + wc * 128 + nj * 16 + cl];

    const int sub = lane >> 3;        // row within 8-row staging block
    const int kb  = (lane & 7) * 8;   // k element offset (16B/lane)

    for (int kk = 0; kk < D_DIM; kk += 64) {
        __syncthreads();
#pragma unroll
        for (int i = 0; i < 12; ++i) {
            int inst = w * 12 + i;    // wave-uniform: 0..47 (16 A + 32 B)
            if (inst < 16) {
                int r = inst * 8 + sub;
                async_copy16(embh + (size_t)(row0 + r) * D_DIM + kk + kb,
                             &As[inst * 512 + lane * 8]);
            } else {
                int blk = inst - 16;
                int r = blk * 8 + sub;
                async_copy16(csh + (size_t)(cbase + r) * D_DIM + kk + kb,
                             &Bs[blk * 512 + lane * 8]);
            }
        }
        __syncthreads();
#pragma unroll
        for (int ks = 0; ks < 64; ks += 32) {
            half8 af[4], bf[8];
#pragma unroll
            for (int mi = 0; mi < 4; ++mi)
                af[mi] = *(const half8*)&As[(wr * 64 + mi * 16 + cl) * 64 + ks + q * 8];
#pragma unroll
            for (int nj = 0; nj < 8; ++nj)
                bf[nj] = *(const half8*)&Bs[(wc * 128 + nj * 16 + cl) * 64 + ks + q * 8];
#pragma unroll
            for (int mi = 0; mi < 4; ++mi)
#pragma unroll
                for (int nj = 0; nj < 8; ++nj)
                    acc[mi][nj] = __builtin_amdgcn_mfma_f32_16x16x32_f16(
                        af[mi], bf[nj], acc[mi][nj], 0, 0, 0);
        }
    }

    // epilogue: per-row min/argmin over the 256-wide tile
    __syncthreads();
    float* smv = (float*)As;            // [128][2]
    int*   smi = (int*)(As + 512);      // 1 KB past smv

#pragma unroll
    for (int mi = 0; mi < 4; ++mi) {
#pragma unroll
        for (int r = 0; r < 4; ++r) {
            float v = 3.4e38f; int idx = 0x7fffffff;
#pragma unroll
            for (int nj = 0; nj < 8; ++nj) {   // ascending col per lane, strict <
                float d = cn_l[nj] - 2.f * acc[mi][nj][r];
                int   c = cbase + wc * 128 + nj * 16 + cl;
                if (d < v) { v = d; idx = c; }
            }
#pragma unroll
            for (int mk = 1; mk <= 8; mk <<= 1) {
                float v2 = __shfl_xor(v, mk, 64);
                int   i2 = __shfl_xor(idx, mk, 64);
                if (v2 < v || (v2 == v && i2 < idx)) { v = v2; idx = i2; }
            }
            if (cl == 0) {
                int rl = wr * 64 + mi * 16 + q * 4 + r;
                smv[rl * 2 + wc] = v;
                smi[rl * 2 + wc] = idx;
            }
        }
    }
    __syncthreads();
    if (tid < 128) {
        float v = smv[tid * 2];      int i = smi[tid * 2];
        float v1 = smv[tid * 2 + 1]; int i1 = smi[tid * 2 + 1];
        if (v1 < v) { v = v1; i = i1; }   // wc0 indices always < wc1 indices
        pvals[(size_t)(row0 + tid) * NTILES2 + blockIdx.y] = v;
        pidx[(size_t)(row0 + tid) * NTILES2 + blockIdx.y]  = i;
    }
}

// ------------------------- partial-min reduce + EXACT fp32 rescore ----
__global__ void reduce_rescore_kernel(const float* __restrict__ pvals,
                                      const int* __restrict__ pidx,
                                      const float* __restrict__ emb,
                                      const float* __restrict__ cs,
                                      float* __restrict__ scores,
                                      int* __restrict__ loc) {
    int w = threadIdx.x >> 6, lane = threadIdx.x & 63;
    int m = blockIdx.x * 4 + w;
    float v = pvals[(size_t)m * NTILES2 + lane];
    int   i = pidx[(size_t)m * NTILES2 + lane];
#pragma unroll
    for (int mk = 1; mk <= 32; mk <<= 1) {
        float v2 = __shfl_xor(v, mk, 64);
        int   i2 = __shfl_xor(i, mk, 64);
        if (v2 < v || (v2 == v && i2 < i)) { v = v2; i = i2; }
    }
    // exact fp32 distance to the selected coreset row
    const float* a = emb + (size_t)m * D_DIM;
    const float* b = cs + (size_t)i * D_DIM;
    float s = 0.f;
#pragma unroll
    for (int t = 0; t < D_DIM / 64; ++t) {
        float d = a[lane + t * 64] - b[lane + t * 64];
        s += d * d;
    }
#pragma unroll
    for (int mk = 1; mk <= 32; mk <<= 1) s += __shfl_xor(s, mk, 64);
    if (lane == 0) { scores[m] = sqrtf(s); loc[m] = i; }
}

// ---------------------------------------------------- per-batch argmax ----
__global__ void argmax_kernel(const float* __restrict__ scores,
                              const int* __restrict__ loc,
                              float* __restrict__ bscore,
                              int* __restrict__ bnn, int* __restrict__ bpatch) {
    int b = blockIdx.x;
    int tid = threadIdx.x;
    float bv = -1.f;
    int bp = 0x7fffffff;
    for (int p = tid; p < P_PATCH; p += 256) {
        float v = scores[b * P_PATCH + p];
        if (v > bv || (v == bv && p < bp)) { bv = v; bp = p; }
    }
    __shared__ float sv[256];
    __shared__ int   sp[256];
    sv[tid] = bv; sp[tid] = bp;
    __syncthreads();
    for (int off = 128; off > 0; off >>= 1) {
        if (tid < off) {
            float v = sv[tid + off]; int p = sp[tid + off];
            if (v > sv[tid] || (v == sv[tid] && p < sp[tid])) { sv[tid] = v; sp[tid] = p; }
        }
        __syncthreads();
    }
    if (tid == 0) {
        bscore[b] = sv[0];
        bpatch[b] = sp[0];
        bnn[b]    = loc[b * P_PATCH + sp[0]];
    }
}

// -------------------- d_nn: 8 queries x 16384 coreset (coalesced GEMV) ----
// wave per row-group; lane covers 6 consecutive floats of the row.
__global__ void dnn_kernel(const float* __restrict__ cs,
                           const float* __restrict__ cnorm,
                           const int* __restrict__ bnn,
                           float* __restrict__ dmat) {
    int lane = threadIdx.x & 63;
    int gw = (blockIdx.x * 256 + threadIdx.x) >> 6;  // 0..1023
    float qv[BATCH][6];
#pragma unroll
    for (int b = 0; b < BATCH; ++b) {
        const float* qr = cs + (size_t)bnn[b] * D_DIM + lane * 6;
#pragma unroll
        for (int j = 0; j < 6; ++j) qv[b][j] = qr[j];
    }
    for (int n = gw; n < N_CS; n += 1024) {
        const float* r = cs + (size_t)n * D_DIM + lane * 6;
        float x[6];
#pragma unroll
        for (int j = 0; j < 6; ++j) x[j] = r[j];
        float s[BATCH];
#pragma unroll
        for (int b = 0; b < BATCH; ++b) {
            float t = 0.f;
#pragma unroll
            for (int j = 0; j < 6; ++j) t += x[j] * qv[b][j];
            s[b] = t;
        }
#pragma unroll
        for (int b = 0; b < BATCH; ++b)
#pragma unroll
            for (int mk = 1; mk <= 32; mk <<= 1) s[b] += __shfl_xor(s[b], mk, 64);
        if (lane < BATCH) {
            float sv = s[0];
#pragma unroll
            for (int b = 1; b < BATCH; ++b) sv = (lane == b) ? s[b] : sv;
            dmat[(size_t)lane * N_CS + n] = cnorm[n] - 2.f * sv;  // -qnorm shift: order-safe
        }
    }
}

// ----------------------- top-9 merge + exact dsup + softmax weighting ----
__device__ inline void merge9(float* av, int* ai, const float* bv, const int* bi) {
    float mv[KNN]; int mi[KNN];
    int x = 0, y = 0;
#pragma unroll
    for (int k = 0; k < KNN; ++k) {
        bool ta = (av[x] < bv[y]) || (av[x] == bv[y] && ai[x] < bi[y]);
        if (ta) { mv[k] = av[x]; mi[k] = ai[x]; ++x; }
        else    { mv[k] = bv[y]; mi[k] = bi[y]; ++y; }
    }
#pragma unroll
    for (int k = 0; k < KNN; ++k) { av[k] = mv[k]; ai[k] = mi[k]; }
}

__global__ void top9_final_kernel(const float* __restrict__ dmat,
                                  const float* __restrict__ emb,
                                  const float* __restrict__ cs,
                                  const float* __restrict__ bscore,
                                  const int* __restrict__ bpatch,
                                  float* __restrict__ out) {
    int b = blockIdx.x;
    int tid = threadIdx.x;  // 256
    __shared__ float lv[256][KNN];
    __shared__ int   li[256][KNN];
    __shared__ float mf[D_DIM];
    __shared__ float dsup[KNN];

    int mp = bpatch[b];
    const float* frow = emb + (size_t)(b * P_PATCH + mp) * D_DIM;
    for (int i = tid; i < D_DIM; i += 256) mf[i] = frow[i];

    float tv[KNN]; int ti[KNN];
#pragma unroll
    for (int k = 0; k < KNN; ++k) { tv[k] = 3.4e38f; ti[k] = 0x7fffffff; }
    for (int n = tid; n < N_CS; n += 256) {   // ascending n per thread
        float d = dmat[(size_t)b * N_CS + n];
        if (d < tv[KNN - 1] || (d == tv[KNN - 1] && n < ti[KNN - 1])) {
            tv[KNN - 1] = d; ti[KNN - 1] = n;
#pragma unroll
            for (int k = KNN - 1; k > 0; --k) {
                if (tv[k] < tv[k - 1] || (tv[k] == tv[k - 1] && ti[k] < ti[k - 1])) {
                    float fv = tv[k]; tv[k] = tv[k - 1]; tv[k - 1] = fv;
                    int   iv = ti[k]; ti[k] = ti[k - 1]; ti[k - 1] = iv;
                }
            }
        }
    }
#pragma unroll
    for (int k = 0; k < KNN; ++k) { lv[tid][k] = tv[k]; li[tid][k] = ti[k]; }
    __syncthreads();
    for (int off = 128; off > 0; off >>= 1) {
        if (tid < off) {
            float av[KNN]; int ai[KNN]; float bv2[KNN]; int bi2[KNN];
#pragma unroll
            for (int k = 0; k < KNN; ++k) {
                av[k]  = lv[tid][k];        ai[k]  = li[tid][k];
                bv2[k] = lv[tid + off][k];  bi2[k] = li[tid + off][k];
            }
            merge9(av, ai, bv2, bi2);
#pragma unroll
            for (int k = 0; k < KNN; ++k) { lv[tid][k] = av[k]; li[tid][k] = ai[k]; }
        }
        __syncthreads();
    }
    if (tid < KNN) {
        int idx = li[0][tid];
        const float* r = cs + (size_t)idx * D_DIM;
        float s = 0.f;
        for (int i = 0; i < D_DIM; ++i) {
            float df = mf[i] - r[i];
            s += df * df;
        }
        dsup[tid] = sqrtf(fmaxf(s, 0.f));
    }
    __syncthreads();
    if (tid == 0) {
        float mx = dsup[0];
        for (int k = 1; k < KNN; ++k) mx = fmaxf(mx, dsup[k]);
        float sum = 0.f, e0 = 0.f;
        for (int k = 0; k < KNN; ++k) {
            float e = expf(dsup[k] - mx);
            sum += e;
            if (k == 0) e0 = e;
        }
        out[b] = (1.f - e0 / sum) * bscore[b];
    }
}

// ------------------------------------------------------------- launcher ----
extern "C" void kernel_launch(void* const* d_in, const int* in_sizes, int n_in,
                              void* d_out, int out_size, void* d_ws, size_t ws_size,
                              hipStream_t stream) {
    (void)in_sizes; (void)n_in; (void)out_size; (void)ws_size;
    const float* emb = (const float*)d_in[0];
    const float* cs  = (const float*)d_in[1];
    float* out = (float*)d_out;

    // workspace layout
    char* p = (char*)d_ws;
    float* cnorm  = (float*)p;  p += (size_t)N_CS * 4;                     // 64 KB
    float* pvals  = (float*)p;  p += (size_t)M_TOTAL * NTILES2 * 4;        // 1.6 MB
    int*   pidx   = (int*)p;    p += (size_t)M_TOTAL * NTILES2 * 4;        // 1.6 MB
    float* scores = (float*)p;  p += (size_t)M_TOTAL * 4;
    int*   loc    = (int*)p;    p += (size_t)M_TOTAL * 4;
    float* bscore = (float*)p;  p += BATCH * 4;
    int*   bpatch = (int*)p;    p += BATCH * 4;
    int*   bnn    = (int*)p;    p += BATCH * 4;
    float* dmat   = (float*)p;  p += (size_t)BATCH * N_CS * 4;             // 512 KB
    p = (char*)(((size_t)p + 15) & ~(size_t)15);
    _Float16* embh = (_Float16*)p; p += (size_t)M_TOTAL * D_DIM * 2;       // 4.8 MB
    _Float16* csh  = (_Float16*)p; p += (size_t)N_CS * D_DIM * 2;          // 12.6 MB

    convert_emb_kernel<<<M_TOTAL / 4, 256, 0, stream>>>(emb, embh);
    convert_cs_kernel<<<N_CS / 4, 256, 0, stream>>>(cs, csh, cnorm);
    {
        dim3 grid(MTILES, NTILES2);
        mindist_mfma_kernel<<<grid, 256, 0, stream>>>(embh, csh, cnorm, pvals, pidx);
    }
    reduce_rescore_kernel<<<M_TOTAL / 4, 256, 0, stream>>>(pvals, pidx, emb, cs, scores, loc);
    argmax_kernel<<<BATCH, 256, 0, stream>>>(scores, loc, bscore, bnn, bpatch);
    dnn_kernel<<<256, 256, 0, stream>>>(cs, cnorm, bnn, dmat);
    top9_final_kernel<<<BATCH, 256, 0, stream>>>(dmat, emb, cs, bscore, bpatch, out);
}

// Round 5
// 306.697 us; speedup vs baseline: 22.8047x; 1.0948x over previous
//
#include <hip/hip_runtime.h>
#include <hip/hip_bf16.h>
#include <math.h>

// Problem constants (fixed by setup_inputs)
#define M_TOTAL 6272   // B*P
#define N_CS    16384  // coreset rows
#define D_DIM   384
#define BATCH   8
#define P_PATCH 784
#define KNN     9

// MFMA GEMM tiling: 128x256 tile, 4 waves (2x2 of 64x128), BK=64
#define MTILES  (M_TOTAL / 128)  // 49
#define NTILES2 (N_CS / 256)     // 64 -> pvals[m][64]

typedef _Float16 half8 __attribute__((ext_vector_type(8)));
typedef float    floatx4 __attribute__((ext_vector_type(4)));

// async global->LDS, 16B per lane; LDS dest must be uniform-base + lane*16
__device__ __forceinline__ void async_copy16(const void* g, void* l) {
    __builtin_amdgcn_global_load_lds(
        (const __attribute__((address_space(1))) void*)g,
        (__attribute__((address_space(3))) void*)l, 16, 0, 0);
}

// ---------------- convert fp32->f16, fused cs+emb (wave per row) ----------
// rows [0, N_CS) -> cs (+cnorm), rows [N_CS, N_CS+M_TOTAL) -> emb.
__global__ void convert_all_kernel(const float* __restrict__ emb,
                                   const float* __restrict__ cs,
                                   _Float16* __restrict__ embh,
                                   _Float16* __restrict__ csh,
                                   float* __restrict__ cnorm) {
    int w = threadIdx.x >> 6, lane = threadIdx.x & 63;
    int row = blockIdx.x * 4 + w;
    if (row >= N_CS + M_TOTAL) return;
    bool is_cs = row < N_CS;
    const float* r = (is_cs ? cs + (size_t)row * D_DIM
                            : emb + (size_t)(row - N_CS) * D_DIM) + lane * 6;
    float2 a = *(const float2*)r;
    float2 b = *(const float2*)(r + 2);
    float2 c = *(const float2*)(r + 4);
    union { _Float16 h[2]; unsigned u; } p0, p1, p2;
    p0.h[0] = (_Float16)a.x; p0.h[1] = (_Float16)a.y;
    p1.h[0] = (_Float16)b.x; p1.h[1] = (_Float16)b.y;
    p2.h[0] = (_Float16)c.x; p2.h[1] = (_Float16)c.y;
    unsigned* dst = (unsigned*)(is_cs ? csh + (size_t)row * D_DIM
                                      : embh + (size_t)(row - N_CS) * D_DIM) + lane * 3;
    dst[0] = p0.u; dst[1] = p1.u; dst[2] = p2.u;
    if (is_cs) {
        float s = a.x * a.x + a.y * a.y + b.x * b.x + b.y * b.y + c.x * c.x + c.y * c.y;
#pragma unroll
        for (int mk = 1; mk <= 32; mk <<= 1) s += __shfl_xor(s, mk, 64);
        if (lane == 0) cnorm[row] = s;
    }
}

// --------------------------------------------- MFMA GEMM + min/argmin ----
// grid (49, 64); block 256 = 4 waves in 2x2 of 64x128 subtiles, BK=64.
// LDS layout is XOR-swizzled: LDS[row][chunk c] = global[row][c ^ (row&7)]
// (16B chunks). Applied on the staging SOURCE address so the lds-dma dest
// stays lane-contiguous. Kills the 16-way bank conflict of row-major
// fragment reads (R4: SQ_LDS_BANK_CONFLICT = 2.2e7 ~ 20% of cycles).
__global__ __launch_bounds__(256, 2) void mindist_mfma_kernel(
    const _Float16* __restrict__ embh, const _Float16* __restrict__ csh,
    const float* __restrict__ cnorm,
    float* __restrict__ pvals, int* __restrict__ pidx) {
    __shared__ _Float16 As[128 * 64];   // 16 KB
    __shared__ _Float16 Bs[256 * 64];   // 32 KB

    const int tid  = threadIdx.x;
    const int lane = tid & 63;
    const int w    = tid >> 6;
    const int wr   = w >> 1, wc = w & 1;
    const int row0  = blockIdx.x * 128;
    const int cbase = blockIdx.y * 256;
    const int q   = lane >> 4;
    const int cl  = lane & 15;
    const int cl7 = cl & 7;

    floatx4 acc[4][8];
#pragma unroll
    for (int mi = 0; mi < 4; ++mi)
#pragma unroll
        for (int nj = 0; nj < 8; ++nj) acc[mi][nj] = (floatx4){0.f, 0.f, 0.f, 0.f};

    float cn_l[8];
#pragma unroll
    for (int nj = 0; nj < 8; ++nj)
        cn_l[nj] = cnorm[cbase + wc * 128 + nj * 16 + cl];

    const int sub = lane >> 3;          // row within 8-row staging block
    const int gch = (lane & 7) ^ sub;   // swizzled source 16B-chunk
    const int kb  = gch * 8;            // element offset

    for (int kk = 0; kk < D_DIM; kk += 64) {
        __syncthreads();
#pragma unroll
        for (int i = 0; i < 12; ++i) {
            int inst = w * 12 + i;      // wave-uniform: 0..47 (16 A + 32 B)
            if (inst < 16) {
                int r = inst * 8 + sub;
                async_copy16(embh + (size_t)(row0 + r) * D_DIM + kk + kb,
                             &As[inst * 512 + lane * 8]);
            } else {
                int blk = inst - 16;
                int r = blk * 8 + sub;
                async_copy16(csh + (size_t)(cbase + r) * D_DIM + kk + kb,
                             &Bs[blk * 512 + lane * 8]);
            }
        }
        __syncthreads();
#pragma unroll
        for (int ks = 0; ks < 64; ks += 32) {
            const int ks8 = ks >> 3;
            half8 af[4], bf[8];
#pragma unroll
            for (int mi = 0; mi < 4; ++mi)
                af[mi] = *(const half8*)&As[(wr * 64 + mi * 16 + cl) * 64
                                            + (((ks8 + q) ^ cl7) * 8)];
#pragma unroll
            for (int nj = 0; nj < 8; ++nj)
                bf[nj] = *(const half8*)&Bs[(wc * 128 + nj * 16 + cl) * 64
                                            + (((ks8 + q) ^ cl7) * 8)];
#pragma unroll
            for (int mi = 0; mi < 4; ++mi)
#pragma unroll
                for (int nj = 0; nj < 8; ++nj)
                    acc[mi][nj] = __builtin_amdgcn_mfma_f32_16x16x32_f16(
                        af[mi], bf[nj], acc[mi][nj], 0, 0, 0);
        }
    }

    // epilogue: per-row min/argmin over the 256-wide tile
    __syncthreads();
    float* smv = (float*)As;            // [128][2]
    int*   smi = (int*)(As + 512);      // 1 KB past smv

#pragma unroll
    for (int mi = 0; mi < 4; ++mi) {
#pragma unroll
        for (int r = 0; r < 4; ++r) {
            float v = 3.4e38f; int idx = 0x7fffffff;
#pragma unroll
            for (int nj = 0; nj < 8; ++nj) {   // ascending col per lane, strict <
                float d = cn_l[nj] - 2.f * acc[mi][nj][r];
                int   c = cbase + wc * 128 + nj * 16 + cl;
                if (d < v) { v = d; idx = c; }
            }
#pragma unroll
            for (int mk = 1; mk <= 8; mk <<= 1) {
                float v2 = __shfl_xor(v, mk, 64);
                int   i2 = __shfl_xor(idx, mk, 64);
                if (v2 < v || (v2 == v && i2 < idx)) { v = v2; idx = i2; }
            }
            if (cl == 0) {
                int rl = wr * 64 + mi * 16 + q * 4 + r;
                smv[rl * 2 + wc] = v;
                smi[rl * 2 + wc] = idx;
            }
        }
    }
    __syncthreads();
    if (tid < 128) {
        float v = smv[tid * 2];      int i = smi[tid * 2];
        float v1 = smv[tid * 2 + 1]; int i1 = smi[tid * 2 + 1];
        if (v1 < v) { v = v1; i = i1; }   // wc0 indices always < wc1 indices
        pvals[(size_t)(row0 + tid) * NTILES2 + blockIdx.y] = v;
        pidx[(size_t)(row0 + tid) * NTILES2 + blockIdx.y]  = i;
    }
}

// ------------------------- partial-min reduce + EXACT fp32 rescore ----
__global__ void reduce_rescore_kernel(const float* __restrict__ pvals,
                                      const int* __restrict__ pidx,
                                      const float* __restrict__ emb,
                                      const float* __restrict__ cs,
                                      float* __restrict__ scores,
                                      int* __restrict__ loc) {
    int w = threadIdx.x >> 6, lane = threadIdx.x & 63;
    int m = blockIdx.x * 4 + w;
    float v = pvals[(size_t)m * NTILES2 + lane];
    int   i = pidx[(size_t)m * NTILES2 + lane];
#pragma unroll
    for (int mk = 1; mk <= 32; mk <<= 1) {
        float v2 = __shfl_xor(v, mk, 64);
        int   i2 = __shfl_xor(i, mk, 64);
        if (v2 < v || (v2 == v && i2 < i)) { v = v2; i = i2; }
    }
    // exact fp32 distance to the selected coreset row
    const float* a = emb + (size_t)m * D_DIM;
    const float* b = cs + (size_t)i * D_DIM;
    float s = 0.f;
#pragma unroll
    for (int t = 0; t < D_DIM / 64; ++t) {
        float d = a[lane + t * 64] - b[lane + t * 64];
        s += d * d;
    }
#pragma unroll
    for (int mk = 1; mk <= 32; mk <<= 1) s += __shfl_xor(s, mk, 64);
    if (lane == 0) { scores[m] = sqrtf(s); loc[m] = i; }
}

// ---------------------------------------------------- per-batch argmax ----
__global__ void argmax_kernel(const float* __restrict__ scores,
                              const int* __restrict__ loc,
                              float* __restrict__ bscore,
                              int* __restrict__ bnn, int* __restrict__ bpatch) {
    int b = blockIdx.x;
    int tid = threadIdx.x;
    float bv = -1.f;
    int bp = 0x7fffffff;
    for (int p = tid; p < P_PATCH; p += 256) {
        float v = scores[b * P_PATCH + p];
        if (v > bv || (v == bv && p < bp)) { bv = v; bp = p; }
    }
    __shared__ float sv[256];
    __shared__ int   sp[256];
    sv[tid] = bv; sp[tid] = bp;
    __syncthreads();
    for (int off = 128; off > 0; off >>= 1) {
        if (tid < off) {
            float v = sv[tid + off]; int p = sp[tid + off];
            if (v > sv[tid] || (v == sv[tid] && p < sp[tid])) { sv[tid] = v; sp[tid] = p; }
        }
        __syncthreads();
    }
    if (tid == 0) {
        bscore[b] = sv[0];
        bpatch[b] = sp[0];
        bnn[b]    = loc[b * P_PATCH + sp[0]];
    }
}

// -------------------- d_nn: 8 queries x 16384 coreset (coalesced GEMV) ----
__global__ void dnn_kernel(const float* __restrict__ cs,
                           const float* __restrict__ cnorm,
                           const int* __restrict__ bnn,
                           float* __restrict__ dmat) {
    int lane = threadIdx.x & 63;
    int gw = (blockIdx.x * 256 + threadIdx.x) >> 6;  // 0..1023
    float qv[BATCH][6];
#pragma unroll
    for (int b = 0; b < BATCH; ++b) {
        const float* qr = cs + (size_t)bnn[b] * D_DIM + lane * 6;
#pragma unroll
        for (int j = 0; j < 6; ++j) qv[b][j] = qr[j];
    }
    for (int n = gw; n < N_CS; n += 1024) {
        const float* r = cs + (size_t)n * D_DIM + lane * 6;
        float x[6];
#pragma unroll
        for (int j = 0; j < 6; ++j) x[j] = r[j];
        float s[BATCH];
#pragma unroll
        for (int b = 0; b < BATCH; ++b) {
            float t = 0.f;
#pragma unroll
            for (int j = 0; j < 6; ++j) t += x[j] * qv[b][j];
            s[b] = t;
        }
#pragma unroll
        for (int b = 0; b < BATCH; ++b)
#pragma unroll
            for (int mk = 1; mk <= 32; mk <<= 1) s[b] += __shfl_xor(s[b], mk, 64);
        if (lane < BATCH) {
            float sv = s[0];
#pragma unroll
            for (int b = 1; b < BATCH; ++b) sv = (lane == b) ? s[b] : sv;
            dmat[(size_t)lane * N_CS + n] = cnorm[n] - 2.f * sv;  // -qnorm shift: order-safe
        }
    }
}

// ----------------------- top-9 merge + exact dsup + softmax weighting ----
__device__ inline void merge9(float* av, int* ai, const float* bv, const int* bi) {
    float mv[KNN]; int mi[KNN];
    int x = 0, y = 0;
#pragma unroll
    for (int k = 0; k < KNN; ++k) {
        bool ta = (av[x] < bv[y]) || (av[x] == bv[y] && ai[x] < bi[y]);
        if (ta) { mv[k] = av[x]; mi[k] = ai[x]; ++x; }
        else    { mv[k] = bv[y]; mi[k] = bi[y]; ++y; }
    }
#pragma unroll
    for (int k = 0; k < KNN; ++k) { av[k] = mv[k]; ai[k] = mi[k]; }
}

__global__ void top9_final_kernel(const float* __restrict__ dmat,
                                  const float* __restrict__ emb,
                                  const float* __restrict__ cs,
                                  const float* __restrict__ bscore,
                                  const int* __restrict__ bpatch,
                                  float* __restrict__ out) {
    int b = blockIdx.x;
    int tid = threadIdx.x;  // 512
    __shared__ float lv[512][KNN];
    __shared__ int   li[512][KNN];
    __shared__ float mf[D_DIM];
    __shared__ float dsup[KNN];

    int mp = bpatch[b];
    const float* frow = emb + (size_t)(b * P_PATCH + mp) * D_DIM;
    for (int i = tid; i < D_DIM; i += 512) mf[i] = frow[i];

    float tv[KNN]; int ti[KNN];
#pragma unroll
    for (int k = 0; k < KNN; ++k) { tv[k] = 3.4e38f; ti[k] = 0x7fffffff; }
    for (int n = tid; n < N_CS; n += 512) {   // ascending n per thread
        float d = dmat[(size_t)b * N_CS + n];
        if (d < tv[KNN - 1] || (d == tv[KNN - 1] && n < ti[KNN - 1])) {
            tv[KNN - 1] = d; ti[KNN - 1] = n;
#pragma unroll
            for (int k = KNN - 1; k > 0; --k) {
                if (tv[k] < tv[k - 1] || (tv[k] == tv[k - 1] && ti[k] < ti[k - 1])) {
                    float fv = tv[k]; tv[k] = tv[k - 1]; tv[k - 1] = fv;
                    int   iv = ti[k]; ti[k] = ti[k - 1]; ti[k - 1] = iv;
                }
            }
        }
    }
#pragma unroll
    for (int k = 0; k < KNN; ++k) { lv[tid][k] = tv[k]; li[tid][k] = ti[k]; }
    __syncthreads();
    for (int off = 256; off > 0; off >>= 1) {
        if (tid < off) {
            float av[KNN]; int ai[KNN]; float bv2[KNN]; int bi2[KNN];
#pragma unroll
            for (int k = 0; k < KNN; ++k) {
                av[k]  = lv[tid][k];        ai[k]  = li[tid][k];
                bv2[k] = lv[tid + off][k];  bi2[k] = li[tid + off][k];
            }
            merge9(av, ai, bv2, bi2);
#pragma unroll
            for (int k = 0; k < KNN; ++k) { lv[tid][k] = av[k]; li[tid][k] = ai[k]; }
        }
        __syncthreads();
    }
    // exact fp32 distances to the 9 support rows: 32 lanes per neighbor
    {
        int k      = tid >> 5;   // 0..15
        int lane32 = tid & 31;
        if (k < KNN) {
            int idx = li[0][k];
            const float* r = cs + (size_t)idx * D_DIM;
            float s = 0.f;
            for (int i = lane32; i < D_DIM; i += 32) {
                float df = mf[i] - r[i];
                s += df * df;
            }
#pragma unroll
            for (int mk = 1; mk <= 16; mk <<= 1) s += __shfl_xor(s, mk, 64);
            if (lane32 == 0) dsup[k] = sqrtf(fmaxf(s, 0.f));
        }
    }
    __syncthreads();
    if (tid == 0) {
        float mx = dsup[0];
        for (int k = 1; k < KNN; ++k) mx = fmaxf(mx, dsup[k]);
        float sum = 0.f, e0 = 0.f;
        for (int k = 0; k < KNN; ++k) {
            float e = expf(dsup[k] - mx);
            sum += e;
            if (k == 0) e0 = e;
        }
        out[b] = (1.f - e0 / sum) * bscore[b];
    }
}

// ------------------------------------------------------------- launcher ----
extern "C" void kernel_launch(void* const* d_in, const int* in_sizes, int n_in,
                              void* d_out, int out_size, void* d_ws, size_t ws_size,
                              hipStream_t stream) {
    (void)in_sizes; (void)n_in; (void)out_size; (void)ws_size;
    const float* emb = (const float*)d_in[0];
    const float* cs  = (const float*)d_in[1];
    float* out = (float*)d_out;

    // workspace layout
    char* p = (char*)d_ws;
    float* cnorm  = (float*)p;  p += (size_t)N_CS * 4;                     // 64 KB
    float* pvals  = (float*)p;  p += (size_t)M_TOTAL * NTILES2 * 4;        // 1.6 MB
    int*   pidx   = (int*)p;    p += (size_t)M_TOTAL * NTILES2 * 4;        // 1.6 MB
    float* scores = (float*)p;  p += (size_t)M_TOTAL * 4;
    int*   loc    = (int*)p;    p += (size_t)M_TOTAL * 4;
    float* bscore = (float*)p;  p += BATCH * 4;
    int*   bpatch = (int*)p;    p += BATCH * 4;
    int*   bnn    = (int*)p;    p += BATCH * 4;
    float* dmat   = (float*)p;  p += (size_t)BATCH * N_CS * 4;             // 512 KB
    p = (char*)(((size_t)p + 15) & ~(size_t)15);
    _Float16* embh = (_Float16*)p; p += (size_t)M_TOTAL * D_DIM * 2;       // 4.8 MB
    _Float16* csh  = (_Float16*)p; p += (size_t)N_CS * D_DIM * 2;          // 12.6 MB

    {
        int rows = N_CS + M_TOTAL;
        convert_all_kernel<<<(rows + 3) / 4, 256, 0, stream>>>(emb, cs, embh, csh, cnorm);
    }
    {
        dim3 grid(MTILES, NTILES2);
        mindist_mfma_kernel<<<grid, 256, 0, stream>>>(embh, csh, cnorm, pvals, pidx);
    }
    reduce_rescore_kernel<<<M_TOTAL / 4, 256, 0, stream>>>(pvals, pidx, emb, cs, scores, loc);
    argmax_kernel<<<BATCH, 256, 0, stream>>>(scores, loc, bscore, bnn, bpatch);
    dnn_kernel<<<256, 256, 0, stream>>>(cs, cnorm, bnn, dmat);
    top9_final_kernel<<<BATCH, 512, 0, stream>>>(dmat, emb, cs, bscore, bpatch, out);
}